// Round 1
// baseline (3136.186 us; speedup 1.0000x reference)
//
#include <hip/hip_runtime.h>
#include <hip/hip_bf16.h>

// StencilNet: 6-layer periodic 3x3 CNN + 4x4 stencil contraction.
// Round 0: fp32-VALU compute baseline, bf16 activation storage in d_ws.
// B=8, H=W=256, CH=64, out = sum_s coeffs[...,s] * roll(C)[...,s]

#define HW   256
#define MASK 255
#define CH   64
#define TX   32
#define TY   16
#define CPAD 65   // LDS channel pad: act-read bank aliasing ~2-way (free)

__device__ __forceinline__ float bf2f(unsigned short u) {
    return __uint_as_float(((unsigned int)u) << 16);
}
__device__ __forceinline__ unsigned short f2bf(float f) {
    unsigned int x = __float_as_uint(f);
    return (unsigned short)((x + 0x7fffu + ((x >> 16) & 1u)) >> 16);  // RNE
}

// ---------------- Layer 0: [C,vx,vy] (3ch f32) -> 64ch bf16, ReLU -------------
__global__ __launch_bounds__(512) void k_layer0(
    const float* __restrict__ Cin, const float* __restrict__ vx,
    const float* __restrict__ vy, const float* __restrict__ w0,
    const float* __restrict__ b0, unsigned short* __restrict__ out)
{
    int t  = threadIdx.x;
    int lx = t & 31, ly = t >> 5;
    int x  = blockIdx.x * TX + lx;
    int y  = blockIdx.y * TY + ly;
    int bb = blockIdx.z;
    int pbase = bb * HW * HW;

    float a[27];
#pragma unroll
    for (int ky = 0; ky < 3; ky++) {
        int yy = (y + ky - 1) & MASK;
#pragma unroll
        for (int kx = 0; kx < 3; kx++) {
            int xx  = (x + kx - 1) & MASK;
            int idx = pbase + yy * HW + xx;
            a[(ky * 3 + kx) * 3 + 0] = Cin[idx];
            a[(ky * 3 + kx) * 3 + 1] = vx[idx];
            a[(ky * 3 + kx) * 3 + 2] = vy[idx];
        }
    }

    size_t obase = ((size_t)(pbase + y * HW + x)) * CH;
    for (int c4 = 0; c4 < 4; c4++) {
        float acc[16];
#pragma unroll
        for (int j = 0; j < 16; j++) acc[j] = b0[c4 * 16 + j];
#pragma unroll
        for (int k = 0; k < 27; k++) {
            float av = a[k];
            const float* wq = w0 + k * CH + c4 * 16;   // w0[(tap*3+ci)*64 + co]
#pragma unroll
            for (int j = 0; j < 16; j++) acc[j] = fmaf(av, wq[j], acc[j]);
        }
        unsigned short o[16];
#pragma unroll
        for (int j = 0; j < 16; j++) o[j] = f2bf(fmaxf(acc[j], 0.f));
        *reinterpret_cast<uint4*>(out + obase + c4 * 16)     = *reinterpret_cast<uint4*>(o);
        *reinterpret_cast<uint4*>(out + obase + c4 * 16 + 8) = *reinterpret_cast<uint4*>(o + 8);
    }
}

// ---------------- Mid layers: 64ch bf16 -> 64ch bf16, ReLU --------------------
__global__ __launch_bounds__(512) void k_mid(
    const unsigned short* __restrict__ in, const float* __restrict__ w,
    const float* __restrict__ b, unsigned short* __restrict__ out)
{
    __shared__ float lds[(TY + 2) * (TX + 2) * CPAD];  // 18*34*65*4 = 159120 B

    int t  = threadIdx.x;
    int x0 = blockIdx.x * TX, y0 = blockIdx.y * TY;
    int bb = blockIdx.z;
    size_t pbase = (size_t)bb * HW * HW;

    // Stage halo tile 18x34x64 (bf16 -> f32) into LDS.
    const int TOT = 18 * 34 * 16;   // ushort4 (4ch) granules
    for (int i = t; i < TOT; i += 512) {
        int cg  = i & 15;
        int rc  = i >> 4;
        int col = rc % 34;
        int row = rc / 34;
        int gy  = (y0 + row - 1) & MASK;
        int gx  = (x0 + col - 1) & MASK;
        const unsigned short* p = in + ((pbase + gy * HW + gx) * CH + cg * 4);
        ushort4 v = *reinterpret_cast<const ushort4*>(p);
        float* lp = lds + (row * 34 + col) * CPAD + cg * 4;
        lp[0] = bf2f(v.x); lp[1] = bf2f(v.y); lp[2] = bf2f(v.z); lp[3] = bf2f(v.w);
    }
    __syncthreads();

    int lx = t & 31, ly = t >> 5;
    int x  = x0 + lx, y = y0 + ly;
    size_t obase = (pbase + y * HW + x) * CH;

    for (int c4 = 0; c4 < 4; c4++) {
        float acc[16];
#pragma unroll
        for (int j = 0; j < 16; j++) acc[j] = b[c4 * 16 + j];
#pragma unroll
        for (int ky = 0; ky < 3; ky++) {
#pragma unroll
            for (int kx = 0; kx < 3; kx++) {
                const float* ap = lds + ((ly + ky) * 34 + (lx + kx)) * CPAD;
                const float* wp = w + ((ky * 3 + kx) * CH) * CH + c4 * 16;
#pragma unroll 4
                for (int ci = 0; ci < CH; ci++) {
                    float av = ap[ci];
                    const float* wq = wp + ci * CH;   // wave-uniform -> s_load
#pragma unroll
                    for (int j = 0; j < 16; j++) acc[j] = fmaf(av, wq[j], acc[j]);
                }
            }
        }
        unsigned short o[16];
#pragma unroll
        for (int j = 0; j < 16; j++) o[j] = f2bf(fmaxf(acc[j], 0.f));
        *reinterpret_cast<uint4*>(out + obase + c4 * 16)     = *reinterpret_cast<uint4*>(o);
        *reinterpret_cast<uint4*>(out + obase + c4 * 16 + 8) = *reinterpret_cast<uint4*>(o + 8);
    }
}

// -------- Output layer: 64ch -> 16 coeffs, fused 4x4 stencil dot with C ------
__global__ __launch_bounds__(512) void k_out(
    const unsigned short* __restrict__ in, const float* __restrict__ w,
    const float* __restrict__ b, const float* __restrict__ Cin,
    float* __restrict__ out)
{
    __shared__ float lds[(TY + 2) * (TX + 2) * CPAD];

    int t  = threadIdx.x;
    int x0 = blockIdx.x * TX, y0 = blockIdx.y * TY;
    int bb = blockIdx.z;
    size_t pbase = (size_t)bb * HW * HW;

    const int TOT = 18 * 34 * 16;
    for (int i = t; i < TOT; i += 512) {
        int cg  = i & 15;
        int rc  = i >> 4;
        int col = rc % 34;
        int row = rc / 34;
        int gy  = (y0 + row - 1) & MASK;
        int gx  = (x0 + col - 1) & MASK;
        const unsigned short* p = in + ((pbase + gy * HW + gx) * CH + cg * 4);
        ushort4 v = *reinterpret_cast<const ushort4*>(p);
        float* lp = lds + (row * 34 + col) * CPAD + cg * 4;
        lp[0] = bf2f(v.x); lp[1] = bf2f(v.y); lp[2] = bf2f(v.z); lp[3] = bf2f(v.w);
    }
    __syncthreads();

    int lx = t & 31, ly = t >> 5;
    int x  = x0 + lx, y = y0 + ly;

    float acc[16];
#pragma unroll
    for (int j = 0; j < 16; j++) acc[j] = b[j];
#pragma unroll
    for (int ky = 0; ky < 3; ky++) {
#pragma unroll
        for (int kx = 0; kx < 3; kx++) {
            const float* ap = lds + ((ly + ky) * 34 + (lx + kx)) * CPAD;
            const float* wp = w + ((ky * 3 + kx) * CH) * 16;   // wout[(tap*64+ci)*16+co]
#pragma unroll 4
            for (int ci = 0; ci < CH; ci++) {
                float av = ap[ci];
                const float* wq = wp + ci * 16;
#pragma unroll
                for (int j = 0; j < 16; j++) acc[j] = fmaf(av, wq[j], acc[j]);
            }
        }
    }

    // stencil: out = sum_{i,j} coeffs[i*4+j] * C[y+i-2, x+j-2]  (periodic)
    float r = 0.f;
#pragma unroll
    for (int i = 0; i < 4; i++) {
        int yy = (y + i - 2) & MASK;
#pragma unroll
        for (int j = 0; j < 4; j++) {
            int xx = (x + j - 2) & MASK;
            r = fmaf(acc[i * 4 + j], Cin[pbase + yy * HW + xx], r);
        }
    }
    out[pbase + y * HW + x] = r;
}

extern "C" void kernel_launch(void* const* d_in, const int* in_sizes, int n_in,
                              void* d_out, int out_size, void* d_ws, size_t ws_size,
                              hipStream_t stream)
{
    (void)in_sizes; (void)n_in; (void)out_size; (void)ws_size;
    const float* Cin  = (const float*)d_in[0];
    const float* vx   = (const float*)d_in[1];
    const float* vy   = (const float*)d_in[2];
    const float* w0   = (const float*)d_in[3];
    const float* b0   = (const float*)d_in[4];
    const float* w1   = (const float*)d_in[5];
    const float* b1   = (const float*)d_in[6];
    const float* w2   = (const float*)d_in[7];
    const float* b2   = (const float*)d_in[8];
    const float* w3   = (const float*)d_in[9];
    const float* b3   = (const float*)d_in[10];
    const float* w4   = (const float*)d_in[11];
    const float* b4   = (const float*)d_in[12];
    const float* wout = (const float*)d_in[13];
    const float* bout = (const float*)d_in[14];

    unsigned short* actA = (unsigned short*)d_ws;
    unsigned short* actB = actA + (size_t)8 * HW * HW * CH;   // 2 x 67.1 MB

    dim3 grid(HW / TX, HW / TY, 8);
    dim3 block(512);
    k_layer0<<<grid, block, 0, stream>>>(Cin, vx, vy, w0, b0, actA);
    k_mid  <<<grid, block, 0, stream>>>(actA, w1, b1, actB);
    k_mid  <<<grid, block, 0, stream>>>(actB, w2, b2, actA);
    k_mid  <<<grid, block, 0, stream>>>(actA, w3, b3, actB);
    k_mid  <<<grid, block, 0, stream>>>(actB, w4, b4, actA);
    k_out  <<<grid, block, 0, stream>>>(actA, wout, bout, Cin, (float*)d_out);
}

// Round 2
// 400.022 us; speedup vs baseline: 7.8400x; 7.8400x over previous
//
#include <hip/hip_runtime.h>
#include <hip/hip_bf16.h>

// StencilNet round 1: mid layers on MFMA (16x16x32 bf16 implicit GEMM).
// Layer0 + out layer keep the verified round-0 VALU kernels.

#define HW   256
#define MASK 255
#define CH   64
#define TX   32
#define TY   16
#define CPAD 65

typedef short bf16x8 __attribute__((ext_vector_type(8)));
typedef float f32x4  __attribute__((ext_vector_type(4)));

__device__ __forceinline__ float bf2f(unsigned short u) {
    return __uint_as_float(((unsigned int)u) << 16);
}
__device__ __forceinline__ unsigned short f2bf(float f) {
    unsigned int x = __float_as_uint(f);
    return (unsigned short)((x + 0x7fffu + ((x >> 16) & 1u)) >> 16);  // RNE
}

// ---------------- Layer 0: [C,vx,vy] (3ch f32) -> 64ch bf16, ReLU -------------
__global__ __launch_bounds__(512) void k_layer0(
    const float* __restrict__ Cin, const float* __restrict__ vx,
    const float* __restrict__ vy, const float* __restrict__ w0,
    const float* __restrict__ b0, unsigned short* __restrict__ out)
{
    int t  = threadIdx.x;
    int lx = t & 31, ly = t >> 5;
    int x  = blockIdx.x * TX + lx;
    int y  = blockIdx.y * TY + ly;
    int bb = blockIdx.z;
    int pbase = bb * HW * HW;

    float a[27];
#pragma unroll
    for (int ky = 0; ky < 3; ky++) {
        int yy = (y + ky - 1) & MASK;
#pragma unroll
        for (int kx = 0; kx < 3; kx++) {
            int xx  = (x + kx - 1) & MASK;
            int idx = pbase + yy * HW + xx;
            a[(ky * 3 + kx) * 3 + 0] = Cin[idx];
            a[(ky * 3 + kx) * 3 + 1] = vx[idx];
            a[(ky * 3 + kx) * 3 + 2] = vy[idx];
        }
    }

    size_t obase = ((size_t)(pbase + y * HW + x)) * CH;
    for (int c4 = 0; c4 < 4; c4++) {
        float acc[16];
#pragma unroll
        for (int j = 0; j < 16; j++) acc[j] = b0[c4 * 16 + j];
#pragma unroll
        for (int k = 0; k < 27; k++) {
            float av = a[k];
            const float* wq = w0 + k * CH + c4 * 16;
#pragma unroll
            for (int j = 0; j < 16; j++) acc[j] = fmaf(av, wq[j], acc[j]);
        }
        unsigned short o[16];
#pragma unroll
        for (int j = 0; j < 16; j++) o[j] = f2bf(fmaxf(acc[j], 0.f));
        *reinterpret_cast<uint4*>(out + obase + c4 * 16)     = *reinterpret_cast<uint4*>(o);
        *reinterpret_cast<uint4*>(out + obase + c4 * 16 + 8) = *reinterpret_cast<uint4*>(o + 8);
    }
}

// ------------- Mid layers, MFMA: 64ch bf16 -> 64ch bf16, ReLU ----------------
// Block: 32x32 px tile, 8 waves. Wave: 128 px (8 M-frags) x 64 co (4 N-frags).
// Full 34x34x64 halo in LDS (bf16, XOR-swizzled); weights staged per-tap (8 KB)
// with register prefetch one tap ahead.
#define MT 32   // tile side

__global__ __launch_bounds__(512, 2) void k_mid_mfma(
    const unsigned short* __restrict__ in, const float* __restrict__ w,
    const float* __restrict__ b, unsigned short* __restrict__ out)
{
    __shared__ unsigned short sAct[34 * 34 * CH];  // 147968 B
    __shared__ unsigned short sWb[4096];           // 8192 B: one tap, packed

    const int t    = threadIdx.x;
    const int lane = t & 63;
    const int wid  = t >> 6;       // 0..7
    const int l15  = lane & 15;
    const int l4   = lane >> 4;    // 0..3
    const int x0   = blockIdx.x * MT;
    const int y0   = blockIdx.y * MT;
    const size_t pbase = (size_t)blockIdx.z * HW * HW;

    // ---- stage activation halo 34x34x64 (bf16), swizzled ----
    // granule g: pixel hp = g>>3 (row-major 34x34), channel octet cg = g&7
    // LDS ushort index: hp*64 + ((cg ^ (hp&7))*8)
    for (int g = t; g < 34 * 34 * 8; g += 512) {
        int hp = g >> 3, cg = g & 7;
        int hr = hp / 34, hc = hp - hr * 34;
        int gy = (y0 + hr - 1) & MASK;
        int gx = (x0 + hc - 1) & MASK;
        uint4 v = *reinterpret_cast<const uint4*>(
            in + ((pbase + gy * HW + gx) * CH + cg * 8));
        *reinterpret_cast<uint4*>(&sAct[hp * 64 + ((cg ^ (hp & 7)) << 3)]) = v;
    }

    // ---- weight fetch lambda: thread t covers granule (q=wid -> s,o ; co) ----
    // value j = w[(tap*64 + s*32 + o*8 + j)*64 + co], coalesced over co.
    const int wco  = t & 63;
    const int wq   = t >> 6;             // (s*4 + o)
    const int wci0 = (wq >> 2) * 32 + (wq & 3) * 8;
    float wr[8];
#pragma unroll
    for (int j = 0; j < 8; j++)
        wr[j] = w[(0 * 64 + wci0 + j) * 64 + wco];   // tap 0 prefetch

    __syncthreads();   // act staged (weights tap0 still in flight -> regs)

    // write tap0 weights, prefetch tap1
    {
        unsigned short o8[8];
#pragma unroll
        for (int j = 0; j < 8; j++) o8[j] = f2bf(wr[j]);
        *reinterpret_cast<uint4*>(&sWb[t * 8]) = *reinterpret_cast<uint4*>(o8);
#pragma unroll
        for (int j = 0; j < 8; j++)
            wr[j] = w[(1 * 64 + wci0 + j) * 64 + wco];
    }
    __syncthreads();   // tap0 weights visible

    // ---- accumulators ----
    f32x4 acc[8][4];
    {
        // bias: C/D layout col=l15 (co), so bias value = b[n*16+l15], same for all rows
#pragma unroll
        for (int m = 0; m < 8; m++)
#pragma unroll
            for (int n = 0; n < 4; n++) {
                float bv = b[n * 16 + l15];
                acc[m][n] = (f32x4){bv, bv, bv, bv};
            }
    }

    // per-frag pixel base (halo linear index), lane-dependent
    int pxb[8];
#pragma unroll
    for (int m = 0; m < 8; m++)
        pxb[m] = (4 * wid + (m >> 1)) * 34 + (m & 1) * 16 + l15;

    const int wbbase = (l4 << 9) + (l15 << 3);   // B-frag lane base (ushort idx)

    // ---- tap loop ----
    for (int tap = 0; tap < 9; tap++) {
        const int koff = (tap / 3) * 34 + (tap % 3);   // ky*34 + kx

#pragma unroll
        for (int s = 0; s < 2; s++) {
            bf16x8 bf[4];
#pragma unroll
            for (int n = 0; n < 4; n++)
                bf[n] = *reinterpret_cast<const bf16x8*>(
                    &sWb[wbbase + (s << 11) + (n << 7)]);
            bf16x8 af[8];
            const int o = s * 4 + l4;
#pragma unroll
            for (int m = 0; m < 8; m++) {
                int px  = pxb[m] + koff;
                int off = (px << 6) + (((o ^ px) & 7) << 3);
                af[m] = *reinterpret_cast<const bf16x8*>(&sAct[off]);
            }
#pragma unroll
            for (int m = 0; m < 8; m++)
#pragma unroll
                for (int n = 0; n < 4; n++)
                    acc[m][n] = __builtin_amdgcn_mfma_f32_16x16x32_bf16(
                        af[m], bf[n], acc[m][n], 0, 0, 0);
        }

        __syncthreads();   // all waves done reading sWb for this tap
        if (tap < 8) {
            unsigned short o8[8];
#pragma unroll
            for (int j = 0; j < 8; j++) o8[j] = f2bf(wr[j]);
            *reinterpret_cast<uint4*>(&sWb[t * 8]) = *reinterpret_cast<uint4*>(o8);
            if (tap < 7) {
#pragma unroll
                for (int j = 0; j < 8; j++)
                    wr[j] = w[((tap + 2) * 64 + wci0 + j) * 64 + wco];
            }
            __syncthreads();   // next-tap weights visible
        }
    }

    // ---- epilogue: ReLU -> bf16 -> global ----
    // C/D: row r = l4*4 + j (pixel within frag), col = l15 (co within n-frag)
#pragma unroll
    for (int m = 0; m < 8; m++) {
        int y = y0 + 4 * wid + (m >> 1);
        int x = x0 + (m & 1) * 16;
        unsigned short* pm = out + (pbase + y * HW + x) * CH + (l4 << 8) + l15;
#pragma unroll
        for (int n = 0; n < 4; n++)
#pragma unroll
            for (int j = 0; j < 4; j++)
                pm[j * 64 + n * 16] = f2bf(fmaxf(acc[m][n][j], 0.f));
    }
}

// -------- Output layer: 64ch -> 16 coeffs, fused 4x4 stencil dot with C ------
__global__ __launch_bounds__(512) void k_out(
    const unsigned short* __restrict__ in, const float* __restrict__ w,
    const float* __restrict__ b, const float* __restrict__ Cin,
    float* __restrict__ out)
{
    __shared__ float lds[(TY + 2) * (TX + 2) * CPAD];

    int t  = threadIdx.x;
    int x0 = blockIdx.x * TX, y0 = blockIdx.y * TY;
    int bb = blockIdx.z;
    size_t pbase = (size_t)bb * HW * HW;

    const int TOT = 18 * 34 * 16;
    for (int i = t; i < TOT; i += 512) {
        int cg  = i & 15;
        int rc  = i >> 4;
        int col = rc % 34;
        int row = rc / 34;
        int gy  = (y0 + row - 1) & MASK;
        int gx  = (x0 + col - 1) & MASK;
        const unsigned short* p = in + ((pbase + gy * HW + gx) * CH + cg * 4);
        ushort4 v = *reinterpret_cast<const ushort4*>(p);
        float* lp = lds + (row * 34 + col) * CPAD + cg * 4;
        lp[0] = bf2f(v.x); lp[1] = bf2f(v.y); lp[2] = bf2f(v.z); lp[3] = bf2f(v.w);
    }
    __syncthreads();

    int lx = t & 31, ly = t >> 5;
    int x  = x0 + lx, y = y0 + ly;

    float acc[16];
#pragma unroll
    for (int j = 0; j < 16; j++) acc[j] = b[j];
#pragma unroll
    for (int ky = 0; ky < 3; ky++) {
#pragma unroll
        for (int kx = 0; kx < 3; kx++) {
            const float* ap = lds + ((ly + ky) * 34 + (lx + kx)) * CPAD;
            const float* wp = w + ((ky * 3 + kx) * CH) * 16;
#pragma unroll 4
            for (int ci = 0; ci < CH; ci++) {
                float av = ap[ci];
                const float* wq = wp + ci * 16;
#pragma unroll
                for (int j = 0; j < 16; j++) acc[j] = fmaf(av, wq[j], acc[j]);
            }
        }
    }

    float r = 0.f;
#pragma unroll
    for (int i = 0; i < 4; i++) {
        int yy = (y + i - 2) & MASK;
#pragma unroll
        for (int j = 0; j < 4; j++) {
            int xx = (x + j - 2) & MASK;
            r = fmaf(acc[i * 4 + j], Cin[pbase + yy * HW + xx], r);
        }
    }
    out[pbase + y * HW + x] = r;
}

extern "C" void kernel_launch(void* const* d_in, const int* in_sizes, int n_in,
                              void* d_out, int out_size, void* d_ws, size_t ws_size,
                              hipStream_t stream)
{
    (void)in_sizes; (void)n_in; (void)out_size; (void)ws_size;
    const float* Cin  = (const float*)d_in[0];
    const float* vx   = (const float*)d_in[1];
    const float* vy   = (const float*)d_in[2];
    const float* w0   = (const float*)d_in[3];
    const float* b0   = (const float*)d_in[4];
    const float* w1   = (const float*)d_in[5];
    const float* b1   = (const float*)d_in[6];
    const float* w2   = (const float*)d_in[7];
    const float* b2   = (const float*)d_in[8];
    const float* w3   = (const float*)d_in[9];
    const float* b3   = (const float*)d_in[10];
    const float* w4   = (const float*)d_in[11];
    const float* b4   = (const float*)d_in[12];
    const float* wout = (const float*)d_in[13];
    const float* bout = (const float*)d_in[14];

    unsigned short* actA = (unsigned short*)d_ws;
    unsigned short* actB = actA + (size_t)8 * HW * HW * CH;

    dim3 block(512);
    dim3 grid0(HW / TX, HW / TY, 8);
    dim3 gridM(HW / MT, HW / MT, 8);

    k_layer0  <<<grid0, block, 0, stream>>>(Cin, vx, vy, w0, b0, actA);
    k_mid_mfma<<<gridM, block, 0, stream>>>(actA, w1, b1, actB);
    k_mid_mfma<<<gridM, block, 0, stream>>>(actB, w2, b2, actA);
    k_mid_mfma<<<gridM, block, 0, stream>>>(actA, w3, b3, actB);
    k_mid_mfma<<<gridM, block, 0, stream>>>(actB, w4, b4, actA);
    k_out     <<<grid0, block, 0, stream>>>(actA, wout, bout, Cin, (float*)d_out);
}

// Round 3
// 285.270 us; speedup vs baseline: 10.9937x; 1.4023x over previous
//
#include <hip/hip_runtime.h>
#include <hip/hip_bf16.h>

// StencilNet round 2: mids on MFMA (verified R1) + out layer on MFMA with
// fused stencil contraction. Layer0 keeps the R0 VALU kernel.

#define HW   256
#define MASK 255
#define CH   64
#define TX   32
#define TY   16

typedef short bf16x8 __attribute__((ext_vector_type(8)));
typedef float f32x4  __attribute__((ext_vector_type(4)));

__device__ __forceinline__ float bf2f(unsigned short u) {
    return __uint_as_float(((unsigned int)u) << 16);
}
__device__ __forceinline__ unsigned short f2bf(float f) {
    unsigned int x = __float_as_uint(f);
    return (unsigned short)((x + 0x7fffu + ((x >> 16) & 1u)) >> 16);  // RNE
}

// ---------------- Layer 0: [C,vx,vy] (3ch f32) -> 64ch bf16, ReLU -------------
__global__ __launch_bounds__(512) void k_layer0(
    const float* __restrict__ Cin, const float* __restrict__ vx,
    const float* __restrict__ vy, const float* __restrict__ w0,
    const float* __restrict__ b0, unsigned short* __restrict__ out)
{
    int t  = threadIdx.x;
    int lx = t & 31, ly = t >> 5;
    int x  = blockIdx.x * TX + lx;
    int y  = blockIdx.y * TY + ly;
    int bb = blockIdx.z;
    int pbase = bb * HW * HW;

    float a[27];
#pragma unroll
    for (int ky = 0; ky < 3; ky++) {
        int yy = (y + ky - 1) & MASK;
#pragma unroll
        for (int kx = 0; kx < 3; kx++) {
            int xx  = (x + kx - 1) & MASK;
            int idx = pbase + yy * HW + xx;
            a[(ky * 3 + kx) * 3 + 0] = Cin[idx];
            a[(ky * 3 + kx) * 3 + 1] = vx[idx];
            a[(ky * 3 + kx) * 3 + 2] = vy[idx];
        }
    }

    size_t obase = ((size_t)(pbase + y * HW + x)) * CH;
    for (int c4 = 0; c4 < 4; c4++) {
        float acc[16];
#pragma unroll
        for (int j = 0; j < 16; j++) acc[j] = b0[c4 * 16 + j];
#pragma unroll
        for (int k = 0; k < 27; k++) {
            float av = a[k];
            const float* wq = w0 + k * CH + c4 * 16;
#pragma unroll
            for (int j = 0; j < 16; j++) acc[j] = fmaf(av, wq[j], acc[j]);
        }
        unsigned short o[16];
#pragma unroll
        for (int j = 0; j < 16; j++) o[j] = f2bf(fmaxf(acc[j], 0.f));
        *reinterpret_cast<uint4*>(out + obase + c4 * 16)     = *reinterpret_cast<uint4*>(o);
        *reinterpret_cast<uint4*>(out + obase + c4 * 16 + 8) = *reinterpret_cast<uint4*>(o + 8);
    }
}

// ------------- Mid layers, MFMA: 64ch bf16 -> 64ch bf16, ReLU ----------------
#define MT 32   // tile side

__global__ __launch_bounds__(512, 2) void k_mid_mfma(
    const unsigned short* __restrict__ in, const float* __restrict__ w,
    const float* __restrict__ b, unsigned short* __restrict__ out)
{
    __shared__ unsigned short sAct[34 * 34 * CH];  // 147968 B
    __shared__ unsigned short sWb[4096];           // 8192 B: one tap, packed

    const int t    = threadIdx.x;
    const int lane = t & 63;
    const int wid  = t >> 6;       // 0..7
    const int l15  = lane & 15;
    const int l4   = lane >> 4;    // 0..3
    const int x0   = blockIdx.x * MT;
    const int y0   = blockIdx.y * MT;
    const size_t pbase = (size_t)blockIdx.z * HW * HW;

    for (int g = t; g < 34 * 34 * 8; g += 512) {
        int hp = g >> 3, cg = g & 7;
        int hr = hp / 34, hc = hp - hr * 34;
        int gy = (y0 + hr - 1) & MASK;
        int gx = (x0 + hc - 1) & MASK;
        uint4 v = *reinterpret_cast<const uint4*>(
            in + ((pbase + gy * HW + gx) * CH + cg * 8));
        *reinterpret_cast<uint4*>(&sAct[hp * 64 + ((cg ^ (hp & 7)) << 3)]) = v;
    }

    const int wco  = t & 63;
    const int wq   = t >> 6;
    const int wci0 = (wq >> 2) * 32 + (wq & 3) * 8;
    float wr[8];
#pragma unroll
    for (int j = 0; j < 8; j++)
        wr[j] = w[(0 * 64 + wci0 + j) * 64 + wco];

    __syncthreads();

    {
        unsigned short o8[8];
#pragma unroll
        for (int j = 0; j < 8; j++) o8[j] = f2bf(wr[j]);
        *reinterpret_cast<uint4*>(&sWb[t * 8]) = *reinterpret_cast<uint4*>(o8);
#pragma unroll
        for (int j = 0; j < 8; j++)
            wr[j] = w[(1 * 64 + wci0 + j) * 64 + wco];
    }
    __syncthreads();

    f32x4 acc[8][4];
#pragma unroll
    for (int m = 0; m < 8; m++)
#pragma unroll
        for (int n = 0; n < 4; n++) {
            float bv = b[n * 16 + l15];
            acc[m][n] = (f32x4){bv, bv, bv, bv};
        }

    int pxb[8];
#pragma unroll
    for (int m = 0; m < 8; m++)
        pxb[m] = (4 * wid + (m >> 1)) * 34 + (m & 1) * 16 + l15;

    const int wbbase = (l4 << 9) + (l15 << 3);

    for (int tap = 0; tap < 9; tap++) {
        const int koff = (tap / 3) * 34 + (tap % 3);

#pragma unroll
        for (int s = 0; s < 2; s++) {
            bf16x8 bf[4];
#pragma unroll
            for (int n = 0; n < 4; n++)
                bf[n] = *reinterpret_cast<const bf16x8*>(
                    &sWb[wbbase + (s << 11) + (n << 7)]);
            bf16x8 af[8];
            const int o = s * 4 + l4;
#pragma unroll
            for (int m = 0; m < 8; m++) {
                int px  = pxb[m] + koff;
                int off = (px << 6) + (((o ^ px) & 7) << 3);
                af[m] = *reinterpret_cast<const bf16x8*>(&sAct[off]);
            }
#pragma unroll
            for (int m = 0; m < 8; m++)
#pragma unroll
                for (int n = 0; n < 4; n++)
                    acc[m][n] = __builtin_amdgcn_mfma_f32_16x16x32_bf16(
                        af[m], bf[n], acc[m][n], 0, 0, 0);
        }

        __syncthreads();
        if (tap < 8) {
            unsigned short o8[8];
#pragma unroll
            for (int j = 0; j < 8; j++) o8[j] = f2bf(wr[j]);
            *reinterpret_cast<uint4*>(&sWb[t * 8]) = *reinterpret_cast<uint4*>(o8);
            if (tap < 7) {
#pragma unroll
                for (int j = 0; j < 8; j++)
                    wr[j] = w[((tap + 2) * 64 + wci0 + j) * 64 + wco];
            }
            __syncthreads();
        }
    }

#pragma unroll
    for (int m = 0; m < 8; m++) {
        int y = y0 + 4 * wid + (m >> 1);
        int x = x0 + (m & 1) * 16;
        unsigned short* pm = out + (pbase + y * HW + x) * CH + (l4 << 8) + l15;
#pragma unroll
        for (int n = 0; n < 4; n++)
#pragma unroll
            for (int j = 0; j < 4; j++)
                pm[j * 64 + n * 16] = f2bf(fmaxf(acc[m][n][j], 0.f));
    }
}

// -------- Output layer MFMA: 64ch -> 16 coeffs + fused 4x4 stencil dot -------
// Tile 32x16, 8 waves x 4 M-frags (64 px each). All 9 taps of wout staged in
// LDS pre-packed in B-frag layout -> no barriers in the tap loop.
__global__ __launch_bounds__(512, 2) void k_out_mfma(
    const unsigned short* __restrict__ in, const float* __restrict__ w,
    const float* __restrict__ b, const float* __restrict__ Cin,
    float* __restrict__ out)
{
    __shared__ unsigned short sAct[18 * 34 * CH];   // 78336 B
    __shared__ unsigned short sW[9 * 128 * 8];      // 18432 B
    __shared__ float sC[19 * 35];                   // 2660 B

    const int t    = threadIdx.x;
    const int lane = t & 63;
    const int wid  = t >> 6;       // 0..7 -> rows 2*wid..2*wid+1
    const int l15  = lane & 15;
    const int l4   = lane >> 4;
    const int x0   = blockIdx.x * 32;
    const int y0   = blockIdx.y * 16;
    const size_t pbase = (size_t)blockIdx.z * HW * HW;

    // act halo 18x34x64 bf16, XOR-swizzled (same scheme as mids)
    for (int g = t; g < 18 * 34 * 8; g += 512) {
        int hp = g >> 3, cg = g & 7;
        int hr = hp / 34, hc = hp - hr * 34;
        int gy = (y0 + hr - 1) & MASK;
        int gx = (x0 + hc - 1) & MASK;
        uint4 v = *reinterpret_cast<const uint4*>(
            in + ((pbase + gy * HW + gx) * CH + cg * 8));
        *reinterpret_cast<uint4*>(&sAct[hp * 64 + ((cg ^ (hp & 7)) << 3)]) = v;
    }
    // wout -> B-frag layout: sW[((tap*2+s)*64 + dl)*8 + j] holds
    // w[(tap*64 + s*32 + (dl>>4)*8 + j)*16 + (dl&15)]
    for (int g = t; g < 1152; g += 512) {
        int tap = g >> 7, s = (g >> 6) & 1, dl = g & 63;
        int ci0 = s * 32 + (dl >> 4) * 8;
        int co  = dl & 15;
        unsigned short o8[8];
#pragma unroll
        for (int j = 0; j < 8; j++)
            o8[j] = f2bf(w[(tap * 64 + ci0 + j) * 16 + co]);
        *reinterpret_cast<uint4*>(&sW[g * 8]) = *reinterpret_cast<uint4*>(o8);
    }
    // C halo 19x35 f32 (dy,dx in [-2,1])
    for (int g = t; g < 19 * 35; g += 512) {
        int r = g / 35, c2 = g - r * 35;
        int gy = (y0 + r - 2) & MASK;
        int gx = (x0 + c2 - 2) & MASK;
        sC[g] = Cin[pbase + gy * HW + gx];
    }
    __syncthreads();

    f32x4 acc[4];
    {
        float bv = b[l15];
#pragma unroll
        for (int m = 0; m < 4; m++) acc[m] = (f32x4){bv, bv, bv, bv};
    }

    int pxb[4];
#pragma unroll
    for (int m = 0; m < 4; m++)
        pxb[m] = (2 * wid + (m >> 1)) * 34 + (m & 1) * 16 + l15;

    for (int tap = 0; tap < 9; tap++) {
        const int koff = (tap / 3) * 34 + (tap % 3);
#pragma unroll
        for (int s = 0; s < 2; s++) {
            bf16x8 bf = *reinterpret_cast<const bf16x8*>(
                &sW[((tap * 2 + s) << 9) + (lane << 3)]);
            const int o = s * 4 + l4;
#pragma unroll
            for (int m = 0; m < 4; m++) {
                int px  = pxb[m] + koff;
                int off = (px << 6) + (((o ^ px) & 7) << 3);
                bf16x8 af = *reinterpret_cast<const bf16x8*>(&sAct[off]);
                acc[m] = __builtin_amdgcn_mfma_f32_16x16x32_bf16(
                    af, bf, acc[m], 0, 0, 0);
            }
        }
    }

    // fused stencil: C/D row r=l4*4+j -> pixel x=(m&1)*16+r on tile row py;
    // col l15 = coeff s; lane term = coeff * C[y+(s>>2)-2, x+(s&3)-2];
    // 16-lane xor-reduce over s.
#pragma unroll
    for (int m = 0; m < 4; m++) {
        int py = 2 * wid + (m >> 1);
        int xb = (m & 1) * 16 + l4 * 4;
#pragma unroll
        for (int j = 0; j < 4; j++) {
            int xt = xb + j;
            float v = acc[m][j] * sC[(py + (l15 >> 2)) * 35 + xt + (l15 & 3)];
            v += __shfl_xor(v, 1);
            v += __shfl_xor(v, 2);
            v += __shfl_xor(v, 4);
            v += __shfl_xor(v, 8);
            if (l15 == 0)
                out[pbase + (y0 + py) * HW + x0 + xt] = v;
        }
    }
}

extern "C" void kernel_launch(void* const* d_in, const int* in_sizes, int n_in,
                              void* d_out, int out_size, void* d_ws, size_t ws_size,
                              hipStream_t stream)
{
    (void)in_sizes; (void)n_in; (void)out_size; (void)ws_size;
    const float* Cin  = (const float*)d_in[0];
    const float* vx   = (const float*)d_in[1];
    const float* vy   = (const float*)d_in[2];
    const float* w0   = (const float*)d_in[3];
    const float* b0   = (const float*)d_in[4];
    const float* w1   = (const float*)d_in[5];
    const float* b1   = (const float*)d_in[6];
    const float* w2   = (const float*)d_in[7];
    const float* b2   = (const float*)d_in[8];
    const float* w3   = (const float*)d_in[9];
    const float* b3   = (const float*)d_in[10];
    const float* w4   = (const float*)d_in[11];
    const float* b4   = (const float*)d_in[12];
    const float* wout = (const float*)d_in[13];
    const float* bout = (const float*)d_in[14];

    unsigned short* actA = (unsigned short*)d_ws;
    unsigned short* actB = actA + (size_t)8 * HW * HW * CH;

    dim3 block(512);
    dim3 grid0(HW / TX, HW / TY, 8);
    dim3 gridM(HW / MT, HW / MT, 8);
    dim3 gridO(HW / 32, HW / 16, 8);

    k_layer0  <<<grid0, block, 0, stream>>>(Cin, vx, vy, w0, b0, actA);
    k_mid_mfma<<<gridM, block, 0, stream>>>(actA, w1, b1, actB);
    k_mid_mfma<<<gridM, block, 0, stream>>>(actB, w2, b2, actA);
    k_mid_mfma<<<gridM, block, 0, stream>>>(actA, w3, b3, actB);
    k_mid_mfma<<<gridM, block, 0, stream>>>(actB, w4, b4, actA);
    k_out_mfma<<<gridO, block, 0, stream>>>(actA, wout, bout, Cin, (float*)d_out);
}